// Round 1
// 245.588 us; speedup vs baseline: 1.4074x; 1.4074x over previous
//
#include <hip/hip_runtime.h>
#include <hip/hip_bf16.h>

// EGA layer (GAT-like, GLOBAL per-head softmax over edges) on MI355X.
// Pipeline: MFMA split-GEMM(+fused scores) -> online global softmax -> thresholded scatter.
// GEMM runs on matrix cores via bf16x3 split (x=hi+lo, W=hi+lo, acc hi*hi+hi*lo+lo*hi
// in fp32 MFMA): per-product rel err ~3*2^-18 => output err ~5e-4 << 7e-3 threshold.
// Global softmax over 800K edges with score std ~11 => weight mass concentrated
// in O(100) edges; scatter skips Wh gather + atomics for w < 1e-9.

#define N_NODES 50000
#define N_EDGES 800000
#define IN_DIM  256
#define OUT_DIM 64
#define HEADS   8
#define NCOL    (HEADS * OUT_DIM)   // 512
#define NBLK_RED 1024               // partial-reduction blocks for edge softmax
#define LN_W_EPS (-20.72326584f)    // ln(1e-9) skip threshold

typedef __attribute__((ext_vector_type(8))) short short8;   // 8 x bf16 (4 VGPRs)
typedef __attribute__((ext_vector_type(4))) float f32x4;

// RNE bf16 hi + trunc bf16 lo split of 2 floats -> packed u32s (lane-order j, j+1)
__device__ __forceinline__ void bf16_split2(float x0, float x1,
                                            unsigned& hi, unsigned& lo)
{
    unsigned u0 = __float_as_uint(x0), u1 = __float_as_uint(x1);
    unsigned r0 = u0 + 0x7FFFu + ((u0 >> 16) & 1u);   // RNE to bf16
    unsigned r1 = u1 + 0x7FFFu + ((u1 >> 16) & 1u);
    float h0 = __uint_as_float(r0 & 0xFFFF0000u);
    float h1 = __uint_as_float(r1 & 0xFFFF0000u);
    hi = (r0 >> 16) | (r1 & 0xFFFF0000u);
    unsigned l0 = __float_as_uint(x0 - h0);           // residual, trunc to bf16
    unsigned l1 = __float_as_uint(x1 - h1);
    lo = (l0 >> 16) | (l1 & 0xFFFF0000u);
}

// ---------------------------------------------------------------------------
// Pack W (fp32 [8][256][64]) into B-fragment layout, bf16 hi/lo:
//   wp[ct][s][k8][c][j]  (halfs), ct=col-tile(16 cols) 0..31, s=hi/lo,
//   k8=K-chunk-of-8 0..31, c=col-in-tile 0..15, j=0..7.
// B fragment for mfma_16x16x32: lane l -> col=l&15, k=(l>>4)*8+j  => a wave's
// fragment read is 1KB contiguous. Total 512 KB, stays L2-resident.
// ---------------------------------------------------------------------------
__global__ __launch_bounds__(256) void packw_kernel(
    const float* __restrict__ W, short* __restrict__ wp)
{
    const int ct = blockIdx.x;            // 0..31
    const int h  = ct >> 2;               // head (4 col-tiles per head)
    #pragma unroll
    for (int it = 0; it < 2; ++it) {
        const int i  = threadIdx.x + it * 256;   // 512 items: (k8, c)
        const int k8 = i >> 4;
        const int c  = i & 15;
        const int o  = (ct & 3) * 16 + c;
        const float* src = W + (size_t)h * IN_DIM * OUT_DIM
                             + (size_t)k8 * 8 * OUT_DIM + o;
        unsigned hi[4], lo[4];
        #pragma unroll
        for (int p = 0; p < 4; ++p) {
            float x0 = src[(2 * p) * OUT_DIM];
            float x1 = src[(2 * p + 1) * OUT_DIM];
            bf16_split2(x0, x1, hi[p], lo[p]);
        }
        uint4 vh = make_uint4(hi[0], hi[1], hi[2], hi[3]);
        uint4 vl = make_uint4(lo[0], lo[1], lo[2], lo[3]);
        *(uint4*)(wp + (((size_t)(ct * 2 + 0) * 32 + k8) * 128) + c * 8) = vh;
        *(uint4*)(wp + (((size_t)(ct * 2 + 1) * 32 + k8) * 128) + c * 8) = vl;
    }
}

// ---------------------------------------------------------------------------
// MFMA GEMM: Wh[n][h*64+o] = x[n][:] dot W[h][:][o] + b[h][o]  (+fused scores).
// 256 threads = 4 waves; wave w owns one head's 64 cols x 64 rows (4x4 frags
// of 16x16x32). Block stages its 64x256 fp32 x-panel ONCE into LDS as bf16
// hi/lo in A-fragment layout (XOR-swizzled: conflict-free write AND read).
// B fragments come from L2-resident wp. K-loop: 8 steps of 32, reg dbuf.
// Block-id remap pairs the two N-halves of a panel on the SAME XCD (bid,bid+8)
// so x is HBM-fetched once.
// ---------------------------------------------------------------------------
__global__ __launch_bounds__(256, 2) void gemm_kernel(
    const float* __restrict__ x, const short* __restrict__ wp,
    const float* __restrict__ b, const float* __restrict__ a,
    float* __restrict__ Wh, float* __restrict__ s_src, float* __restrict__ s_dst)
{
    // [mi(4)][s(2)][k8(32)][r(16)][j(8)] halfs, 16B chunk index XOR-swizzled
    __shared__ __align__(16) short As[32768];   // 64 KB

    const int bid = blockIdx.x;
    const int pid = (bid >> 4) * 8 + (bid & 7);   // panel id 0..783
    const int nh  = (bid >> 3) & 1;               // N-half
    if (pid >= 782) return;
    const int row0 = pid * 64;

    const int tid  = threadIdx.x;
    const int lane = tid & 63;
    const int w    = tid >> 6;            // wave 0..3
    const int head = nh * 4 + w;
    const int r16  = lane & 15;
    const int kq   = lane >> 4;

    // ---- fill LDS: x panel -> bf16 hi/lo fragment layout (once) ----
    #pragma unroll
    for (int q = 0; q < 8; ++q) {
        const int row  = q * 8 + (tid >> 5);      // 0..63
        const int kc   = tid & 31;                // K-chunk of 8
        const int grow = row0 + row;
        f32x4 v0 = {0.f, 0.f, 0.f, 0.f}, v1 = {0.f, 0.f, 0.f, 0.f};
        if (grow < N_NODES) {
            v0 = *(const f32x4*)(x + (size_t)grow * IN_DIM + kc * 8);
            v1 = *(const f32x4*)(x + (size_t)grow * IN_DIM + kc * 8 + 4);
        }
        unsigned hi[4], lo[4];
        bf16_split2(v0.x, v0.y, hi[0], lo[0]);
        bf16_split2(v0.z, v0.w, hi[1], lo[1]);
        bf16_split2(v1.x, v1.y, hi[2], lo[2]);
        bf16_split2(v1.z, v1.w, hi[3], lo[3]);
        const int mi  = row >> 4, rr = row & 15;
        const int swz = rr ^ (kc & 15);
        uint4 vh = make_uint4(hi[0], hi[1], hi[2], hi[3]);
        uint4 vl = make_uint4(lo[0], lo[1], lo[2], lo[3]);
        *(uint4*)((char*)As + ((((mi * 2 + 0) * 32 + kc) * 16 + swz) * 16)) = vh;
        *(uint4*)((char*)As + ((((mi * 2 + 1) * 32 + kc) * 16 + swz) * 16)) = vl;
    }
    __syncthreads();

    // ---- K-loop ----
    f32x4 acc[4][4] = {};
    const short* pB = wp + (size_t)kq * 128 + (size_t)r16 * 8;

    #define LD_A(mi, s, ks) \
        (*(const short8*)((const char*)As + \
            (((((mi) * 2 + (s)) * 32 + (4 * (ks) + kq)) * 16 + \
              (r16 ^ ((4 * ((ks) & 3) + kq)))) * 16)))
    #define LD_B(ni, s, ks) \
        (*(const short8*)(pB + ((((size_t)(head * 4 + (ni)) * 2 + (s)) * 32 + 4 * (ks)) * 128)))

    short8 Ah[2][4], Al[2][4], Bh[2][4], Bl[2][4];
    #pragma unroll
    for (int mi = 0; mi < 4; ++mi) { Ah[0][mi] = LD_A(mi, 0, 0); Al[0][mi] = LD_A(mi, 1, 0); }
    #pragma unroll
    for (int ni = 0; ni < 4; ++ni) { Bh[0][ni] = LD_B(ni, 0, 0); Bl[0][ni] = LD_B(ni, 1, 0); }

    #pragma unroll
    for (int ks = 0; ks < 8; ++ks) {
        const int cur = ks & 1, nxt = cur ^ 1;
        if (ks < 7) {
            #pragma unroll
            for (int ni = 0; ni < 4; ++ni) {
                Bh[nxt][ni] = LD_B(ni, 0, ks + 1);
                Bl[nxt][ni] = LD_B(ni, 1, ks + 1);
            }
            #pragma unroll
            for (int mi = 0; mi < 4; ++mi) {
                Ah[nxt][mi] = LD_A(mi, 0, ks + 1);
                Al[nxt][mi] = LD_A(mi, 1, ks + 1);
            }
        }
        #pragma unroll
        for (int mi = 0; mi < 4; ++mi)
            #pragma unroll
            for (int ni = 0; ni < 4; ++ni) {
                acc[mi][ni] = __builtin_amdgcn_mfma_f32_16x16x32_bf16(
                    Ah[cur][mi], Bh[cur][ni], acc[mi][ni], 0, 0, 0);
                acc[mi][ni] = __builtin_amdgcn_mfma_f32_16x16x32_bf16(
                    Ah[cur][mi], Bl[cur][ni], acc[mi][ni], 0, 0, 0);
                acc[mi][ni] = __builtin_amdgcn_mfma_f32_16x16x32_bf16(
                    Al[cur][mi], Bh[cur][ni], acc[mi][ni], 0, 0, 0);
            }
    }
    #undef LD_A
    #undef LD_B

    // ---- epilogue: bias, Wh store, fused score dot-products ----
    // C layout (verified): col = lane&15, row = (lane>>4)*4 + reg
    const int n0 = head * 64;
    float bias[4], avs[4], avd[4];
    #pragma unroll
    for (int ni = 0; ni < 4; ++ni) {
        bias[ni] = b[n0 + ni * 16 + r16];
        avs[ni]  = a[head * 128 + ni * 16 + r16];
        avd[ni]  = a[head * 128 + 64 + ni * 16 + r16];
    }
    #pragma unroll
    for (int mi = 0; mi < 4; ++mi) {
        #pragma unroll
        for (int reg = 0; reg < 4; ++reg) {
            const int r = row0 + mi * 16 + kq * 4 + reg;
            float v[4], ps = 0.f, pd = 0.f;
            #pragma unroll
            for (int ni = 0; ni < 4; ++ni) {
                v[ni] = acc[mi][ni][reg] + bias[ni];
                ps += v[ni] * avs[ni];
                pd += v[ni] * avd[ni];
            }
            if (r < N_NODES) {
                float* dst = Wh + (size_t)r * NCOL + n0 + r16;
                dst[0]  = v[0];
                dst[16] = v[1];
                dst[32] = v[2];
                dst[48] = v[3];
            }
            ps += __shfl_xor(ps, 1); pd += __shfl_xor(pd, 1);
            ps += __shfl_xor(ps, 2); pd += __shfl_xor(pd, 2);
            ps += __shfl_xor(ps, 4); pd += __shfl_xor(pd, 4);
            ps += __shfl_xor(ps, 8); pd += __shfl_xor(pd, 8);
            if (r16 == 0 && r < N_NODES) {
                s_src[r * 8 + head] = ps;
                s_dst[r * 8 + head] = pd;
            }
        }
    }
}

// ---------------------------------------------------------------------------
// Online (max, sumexp) over all edges per head. Writes per-block partials.
// ---------------------------------------------------------------------------
__global__ __launch_bounds__(256) void edge_reduce_kernel(
    const int* __restrict__ ei, const float* __restrict__ s_src,
    const float* __restrict__ s_dst, float* __restrict__ partial)
{
    float m[8], l[8];
    #pragma unroll
    for (int h = 0; h < 8; ++h) { m[h] = -1e30f; l[h] = 0.f; }

    for (int e = blockIdx.x * 256 + threadIdx.x; e < N_EDGES; e += gridDim.x * 256) {
        const int row = ei[e];
        const int col = ei[N_EDGES + e];
        const float4 s0 = *(const float4*)(s_src + row * 8);
        const float4 s1 = *(const float4*)(s_src + row * 8 + 4);
        const float4 d0 = *(const float4*)(s_dst + col * 8);
        const float4 d1 = *(const float4*)(s_dst + col * 8 + 4);
        const float ev[8] = { s0.x + d0.x, s0.y + d0.y, s0.z + d0.z, s0.w + d0.w,
                              s1.x + d1.x, s1.y + d1.y, s1.z + d1.z, s1.w + d1.w };
        #pragma unroll
        for (int h = 0; h < 8; ++h) {
            float t = ev[h];
            t = t > 0.f ? t : 0.01f * t;     // leaky_relu 0.01
            if (t > m[h]) { l[h] = l[h] * __expf(m[h] - t) + 1.f; m[h] = t; }
            else          { l[h] += __expf(t - m[h]); }
        }
    }

    __shared__ float red[16][256];
    const int tid = threadIdx.x;
    #pragma unroll
    for (int h = 0; h < 8; ++h) { red[h][tid] = m[h]; red[8 + h][tid] = l[h]; }
    __syncthreads();
    for (int s = 128; s > 0; s >>= 1) {
        if (tid < s) {
            #pragma unroll
            for (int h = 0; h < 8; ++h) {
                float mo = red[h][tid + s], lo = red[8 + h][tid + s];
                float mm = red[h][tid],     ll = red[8 + h][tid];
                if (mo > mm) { ll = ll * __expf(mm - mo) + lo; mm = mo; }
                else         { ll += lo * __expf(mo - mm); }
                red[h][tid] = mm; red[8 + h][tid] = ll;
            }
        }
        __syncthreads();
    }
    if (tid == 0) {
        #pragma unroll
        for (int h = 0; h < 8; ++h) {
            partial[blockIdx.x * 16 + h]     = red[h][0];
            partial[blockIdx.x * 16 + 8 + h] = red[8 + h][0];
        }
    }
}

// ---------------------------------------------------------------------------
// Merge partials. coef[h]=M_h, coef[8+h]=g_h/L_h, coef[16+h]=skip cutoff.
// ---------------------------------------------------------------------------
__global__ void finalize_kernel(const float* __restrict__ partial,
                                const float* __restrict__ gate,
                                float* __restrict__ coef, int nblk)
{
    const int t = threadIdx.x;           // 64 threads: h = t&7, chunk j = t>>3
    const int h = t & 7;
    const int j = t >> 3;
    float m = -1e30f, l = 0.f;
    for (int bk = j; bk < nblk; bk += 8) {
        const float mb = partial[bk * 16 + h];
        const float lb = partial[bk * 16 + 8 + h];
        if (mb > m) { l = l * __expf(m - mb) + lb; m = mb; }
        else        { l += lb * __expf(mb - m); }
    }
    #pragma unroll
    for (int s = 8; s < 64; s <<= 1) {
        const float mo = __shfl_xor(m, s);
        const float lo = __shfl_xor(l, s);
        if (mo > m) { l = l * __expf(m - mo) + lo; m = mo; }
        else        { l += lo * __expf(mo - m); }
    }
    if (j == 0) {
        float gm = gate[0];
        for (int i = 1; i < 8; ++i) gm = fmaxf(gm, gate[i]);
        float gs = 0.f;
        for (int i = 0; i < 8; ++i) gs += __expf(gate[i] - gm);
        const float g = __expf(gate[h] - gm) / gs;
        const float C = g / l;
        coef[h]      = m;
        coef[8 + h]  = C;
        coef[16 + h] = m + LN_W_EPS - __logf(C);   // t >= cut  <=>  w >= eps
    }
}

// ---------------------------------------------------------------------------
// Thresholded scatter. One thread per edge for the cheap score test; the rare
// passing edges are processed wave-cooperatively (lane = output dim o).
// ---------------------------------------------------------------------------
__global__ __launch_bounds__(256) void scatter_kernel(
    const int* __restrict__ ei, const float* __restrict__ s_src,
    const float* __restrict__ s_dst, const float* __restrict__ Wh,
    const float* __restrict__ coef, float* __restrict__ out)
{
    __shared__ float cM[8], cC[8], cCut[8];
    if (threadIdx.x < 8)       cM[threadIdx.x]        = coef[threadIdx.x];
    else if (threadIdx.x < 16) cC[threadIdx.x - 8]    = coef[threadIdx.x];
    else if (threadIdx.x < 24) cCut[threadIdx.x - 16] = coef[threadIdx.x];
    __syncthreads();

    const int lane = threadIdx.x & 63;
    const int e    = blockIdx.x * 256 + threadIdx.x;   // grid == N_EDGES/256

    int row = 0, col = 0;
    bool pass = false;
    float w[8];
    if (e < N_EDGES) {
        row = ei[e];
        col = ei[N_EDGES + e];
        const float4 s0 = *(const float4*)(s_src + row * 8);
        const float4 s1 = *(const float4*)(s_src + row * 8 + 4);
        const float4 d0 = *(const float4*)(s_dst + col * 8);
        const float4 d1 = *(const float4*)(s_dst + col * 8 + 4);
        float t[8] = { s0.x + d0.x, s0.y + d0.y, s0.z + d0.z, s0.w + d0.w,
                       s1.x + d1.x, s1.y + d1.y, s1.z + d1.z, s1.w + d1.w };
        #pragma unroll
        for (int h = 0; h < 8; ++h) {
            t[h] = t[h] > 0.f ? t[h] : 0.01f * t[h];
            pass |= (t[h] >= cCut[h]);
        }
        if (pass) {
            #pragma unroll
            for (int h = 0; h < 8; ++h)
                w[h] = __expf(t[h] - cM[h]) * cC[h];
        }
    }

    unsigned long long mask = __ballot(pass);
    while (mask) {
        const int src = (int)__builtin_ctzll(mask);
        mask &= mask - 1;
        const int rb = __shfl(row, src);
        const int cb = __shfl(col, src);
        const float* wc = Wh + (size_t)cb * NCOL + lane;
        float acc = 0.f;
        #pragma unroll
        for (int h = 0; h < 8; ++h)
            acc += __shfl(w[h], src) * wc[h * 64];
        atomicAdd(out + (size_t)rb * OUT_DIM + lane, acc);
    }
}

// ---------------------------------------------------------------------------
extern "C" void kernel_launch(void* const* d_in, const int* in_sizes, int n_in,
                              void* d_out, int out_size, void* d_ws, size_t ws_size,
                              hipStream_t stream)
{
    const float* x    = (const float*)d_in[0];
    const int*   ei   = (const int*)  d_in[1];
    const float* W    = (const float*)d_in[2];
    const float* b    = (const float*)d_in[3];
    const float* a    = (const float*)d_in[4];
    const float* gate = (const float*)d_in[5];
    float* out = (float*)d_out;

    // workspace layout (floats): Wh | s_src | s_dst | partial | coef | wp (~106.7 MB)
    float* ws      = (float*)d_ws;
    float* Wh      = ws;
    float* s_src   = Wh    + (size_t)N_NODES * NCOL;
    float* s_dst   = s_src + (size_t)N_NODES * HEADS;
    float* partial = s_dst + (size_t)N_NODES * HEADS;
    float* coef    = partial + (size_t)NBLK_RED * 16;
    short* wp      = (short*)(coef + 32);              // 512 KB, 16B-aligned

    hipMemsetAsync(d_out, 0, (size_t)N_NODES * OUT_DIM * sizeof(float), stream);

    packw_kernel<<<32, 256, 0, stream>>>(W, wp);

    gemm_kernel<<<1568, 256, 0, stream>>>(x, wp, b, a, Wh, s_src, s_dst);

    edge_reduce_kernel<<<NBLK_RED, 256, 0, stream>>>(ei, s_src, s_dst, partial);

    finalize_kernel<<<1, 64, 0, stream>>>(partial, gate, coef, NBLK_RED);

    scatter_kernel<<<(N_EDGES + 255) / 256, 256, 0, stream>>>(
        ei, s_src, s_dst, Wh, coef, out);
}

// Round 2
// 221.773 us; speedup vs baseline: 1.5585x; 1.1074x over previous
//
#include <hip/hip_runtime.h>
#include <hip/hip_bf16.h>

// EGA layer (GAT-like, GLOBAL per-head softmax over edges) on MI355X.
// Pipeline: MFMA split-GEMM(+fused scores) -> edge score pass (writes t + online
// (m,l) partials) -> finalize -> thresholded scatter reading coalesced t-buffer.
// GEMM runs on matrix cores via bf16x3 split (x=hi+lo, W=hi+lo, acc hi*hi+hi*lo+lo*hi
// in fp32 MFMA): per-product rel err ~3*2^-18 => output err ~5e-4 << 7e-3 threshold.
// Global softmax over 800K edges with score std ~11 => weight mass concentrated
// in O(100) edges; scatter skips Wh gather + atomics for w < 1e-9.

#define N_NODES 50000
#define N_EDGES 800000
#define IN_DIM  256
#define OUT_DIM 64
#define HEADS   8
#define NCOL    (HEADS * OUT_DIM)   // 512
#define NBLK_RED 1024               // partial-reduction blocks for edge softmax
#define LN_W_EPS (-20.72326584f)    // ln(1e-9) skip threshold

typedef __attribute__((ext_vector_type(8))) short short8;   // 8 x bf16 (4 VGPRs)
typedef __attribute__((ext_vector_type(4))) float f32x4;

// RNE bf16 hi + trunc bf16 lo split of 2 floats -> packed u32s (lane-order j, j+1)
__device__ __forceinline__ void bf16_split2(float x0, float x1,
                                            unsigned& hi, unsigned& lo)
{
    unsigned u0 = __float_as_uint(x0), u1 = __float_as_uint(x1);
    unsigned r0 = u0 + 0x7FFFu + ((u0 >> 16) & 1u);   // RNE to bf16
    unsigned r1 = u1 + 0x7FFFu + ((u1 >> 16) & 1u);
    float h0 = __uint_as_float(r0 & 0xFFFF0000u);
    float h1 = __uint_as_float(r1 & 0xFFFF0000u);
    hi = (r0 >> 16) | (r1 & 0xFFFF0000u);
    unsigned l0 = __float_as_uint(x0 - h0);           // residual, trunc to bf16
    unsigned l1 = __float_as_uint(x1 - h1);
    lo = (l0 >> 16) | (l1 & 0xFFFF0000u);
}

// ---------------------------------------------------------------------------
// Pack W (fp32 [8][256][64]) into B-fragment layout, bf16 hi/lo:
//   wp[ct][s][k8][c][j]  (halfs), ct=col-tile(16 cols) 0..31, s=hi/lo,
//   k8=K-chunk-of-8 0..31, c=col-in-tile 0..15, j=0..7.
// B fragment for mfma_16x16x32: lane l -> col=l&15, k=(l>>4)*8+j  => a wave's
// fragment read is 1KB contiguous. Total 512 KB, stays L2-resident.
// ---------------------------------------------------------------------------
__global__ __launch_bounds__(256) void packw_kernel(
    const float* __restrict__ W, short* __restrict__ wp)
{
    const int ct = blockIdx.x;            // 0..31
    const int h  = ct >> 2;               // head (4 col-tiles per head)
    #pragma unroll
    for (int it = 0; it < 2; ++it) {
        const int i  = threadIdx.x + it * 256;   // 512 items: (k8, c)
        const int k8 = i >> 4;
        const int c  = i & 15;
        const int o  = (ct & 3) * 16 + c;
        const float* src = W + (size_t)h * IN_DIM * OUT_DIM
                             + (size_t)k8 * 8 * OUT_DIM + o;
        unsigned hi[4], lo[4];
        #pragma unroll
        for (int p = 0; p < 4; ++p) {
            float x0 = src[(2 * p) * OUT_DIM];
            float x1 = src[(2 * p + 1) * OUT_DIM];
            bf16_split2(x0, x1, hi[p], lo[p]);
        }
        uint4 vh = make_uint4(hi[0], hi[1], hi[2], hi[3]);
        uint4 vl = make_uint4(lo[0], lo[1], lo[2], lo[3]);
        *(uint4*)(wp + (((size_t)(ct * 2 + 0) * 32 + k8) * 128) + c * 8) = vh;
        *(uint4*)(wp + (((size_t)(ct * 2 + 1) * 32 + k8) * 128) + c * 8) = vl;
    }
}

// ---------------------------------------------------------------------------
// MFMA GEMM: Wh[n][...] = x[n][:] dot W[h][:][o] + b[h][o]  (+fused scores).
// 512 threads = 8 waves; wave w == head w, 64 rows x 64 cols (4x4 frags of
// 16x16x32). Block stages its 64x256 fp32 x-panel ONCE into LDS as bf16
// hi/lo in A-fragment layout (XOR-swizzled: conflict-free write AND read);
// the one fill serves all 8 heads. B fragments from L2-resident wp.
// 64 KB LDS -> 2 blocks/CU = 4 waves/SIMD (was 2: latency-bound at 16% occ).
// Wh stored PERMUTED [node][h][r16(16)][ni(4)] so the epilogue is float4
// stores; scatter compensates with a permuted in-row gather index.
// ---------------------------------------------------------------------------
__global__ __launch_bounds__(512, 4) void gemm_kernel(
    const float* __restrict__ x, const short* __restrict__ wp,
    const float* __restrict__ b, const float* __restrict__ a,
    float* __restrict__ Wh, float* __restrict__ s_src, float* __restrict__ s_dst)
{
    // [mi(4)][s(2)][k8(32)][r(16)][j(8)] halfs, 16B chunk index XOR-swizzled
    __shared__ __align__(16) short As[32768];   // 64 KB

    const int row0 = blockIdx.x * 64;
    const int tid  = threadIdx.x;
    const int lane = tid & 63;
    const int head = tid >> 6;            // wave == head 0..7
    const int r16  = lane & 15;
    const int kq   = lane >> 4;

    // ---- prefetch B[ks=0] before the fill: L2 latency hides under fill ----
    const short* pB = wp + (size_t)kq * 128 + (size_t)r16 * 8;
    #define LD_B(ni, s, ks) \
        (*(const short8*)(pB + ((((size_t)(head * 4 + (ni)) * 2 + (s)) * 32 + 4 * (ks)) * 128)))
    short8 Bh[2][4], Bl[2][4];
    #pragma unroll
    for (int ni = 0; ni < 4; ++ni) { Bh[0][ni] = LD_B(ni, 0, 0); Bl[0][ni] = LD_B(ni, 1, 0); }

    // ---- fill LDS: x panel -> bf16 hi/lo fragment layout (once per block) ----
    #pragma unroll
    for (int q = 0; q < 4; ++q) {
        const int item = q * 512 + tid;           // 2048 items: (row, kc)
        const int row  = item >> 5;               // 0..63
        const int kc   = item & 31;               // K-chunk of 8
        const int grow = row0 + row;
        f32x4 v0 = {0.f, 0.f, 0.f, 0.f}, v1 = {0.f, 0.f, 0.f, 0.f};
        if (grow < N_NODES) {
            v0 = *(const f32x4*)(x + (size_t)grow * IN_DIM + kc * 8);
            v1 = *(const f32x4*)(x + (size_t)grow * IN_DIM + kc * 8 + 4);
        }
        unsigned hi[4], lo[4];
        bf16_split2(v0.x, v0.y, hi[0], lo[0]);
        bf16_split2(v0.z, v0.w, hi[1], lo[1]);
        bf16_split2(v1.x, v1.y, hi[2], lo[2]);
        bf16_split2(v1.z, v1.w, hi[3], lo[3]);
        const int mi  = row >> 4, rr = row & 15;
        const int swz = rr ^ (kc & 15);
        uint4 vh = make_uint4(hi[0], hi[1], hi[2], hi[3]);
        uint4 vl = make_uint4(lo[0], lo[1], lo[2], lo[3]);
        *(uint4*)((char*)As + ((((mi * 2 + 0) * 32 + kc) * 16 + swz) * 16)) = vh;
        *(uint4*)((char*)As + ((((mi * 2 + 1) * 32 + kc) * 16 + swz) * 16)) = vl;
    }
    __syncthreads();

    // ---- K-loop ----
    f32x4 acc[4][4] = {};

    #define LD_A(mi, s, ks) \
        (*(const short8*)((const char*)As + \
            (((((mi) * 2 + (s)) * 32 + (4 * (ks) + kq)) * 16 + \
              (r16 ^ ((4 * ((ks) & 3) + kq)))) * 16)))

    short8 Ah[2][4], Al[2][4];
    #pragma unroll
    for (int mi = 0; mi < 4; ++mi) { Ah[0][mi] = LD_A(mi, 0, 0); Al[0][mi] = LD_A(mi, 1, 0); }

    #pragma unroll
    for (int ks = 0; ks < 8; ++ks) {
        const int cur = ks & 1, nxt = cur ^ 1;
        if (ks < 7) {
            #pragma unroll
            for (int ni = 0; ni < 4; ++ni) {
                Bh[nxt][ni] = LD_B(ni, 0, ks + 1);
                Bl[nxt][ni] = LD_B(ni, 1, ks + 1);
            }
            #pragma unroll
            for (int mi = 0; mi < 4; ++mi) {
                Ah[nxt][mi] = LD_A(mi, 0, ks + 1);
                Al[nxt][mi] = LD_A(mi, 1, ks + 1);
            }
        }
        #pragma unroll
        for (int mi = 0; mi < 4; ++mi)
            #pragma unroll
            for (int ni = 0; ni < 4; ++ni) {
                acc[mi][ni] = __builtin_amdgcn_mfma_f32_16x16x32_bf16(
                    Ah[cur][mi], Bh[cur][ni], acc[mi][ni], 0, 0, 0);
                acc[mi][ni] = __builtin_amdgcn_mfma_f32_16x16x32_bf16(
                    Ah[cur][mi], Bl[cur][ni], acc[mi][ni], 0, 0, 0);
                acc[mi][ni] = __builtin_amdgcn_mfma_f32_16x16x32_bf16(
                    Al[cur][mi], Bh[cur][ni], acc[mi][ni], 0, 0, 0);
            }
    }
    #undef LD_A
    #undef LD_B

    // ---- epilogue: bias, permuted-Wh float4 store, fused score dots ----
    // C layout (verified): col = lane&15, row = (lane>>4)*4 + reg
    const int n0 = head * 64;
    float bias[4], avs[4], avd[4];
    #pragma unroll
    for (int ni = 0; ni < 4; ++ni) {
        bias[ni] = b[n0 + ni * 16 + r16];
        avs[ni]  = a[head * 128 + ni * 16 + r16];
        avd[ni]  = a[head * 128 + 64 + ni * 16 + r16];
    }
    #pragma unroll
    for (int mi = 0; mi < 4; ++mi) {
        #pragma unroll
        for (int reg = 0; reg < 4; ++reg) {
            const int r = row0 + mi * 16 + kq * 4 + reg;
            float v[4], ps = 0.f, pd = 0.f;
            #pragma unroll
            for (int ni = 0; ni < 4; ++ni) {
                v[ni] = acc[mi][ni][reg] + bias[ni];
                ps += v[ni] * avs[ni];
                pd += v[ni] * avd[ni];
            }
            if (r < N_NODES) {
                // Wh_p[node][head][r16][ni]: element (h, o) at h*64 + (o&15)*4 + (o>>4)
                *(float4*)(Wh + (size_t)r * NCOL + n0 + r16 * 4) =
                    make_float4(v[0], v[1], v[2], v[3]);
            }
            ps += __shfl_xor(ps, 1); pd += __shfl_xor(pd, 1);
            ps += __shfl_xor(ps, 2); pd += __shfl_xor(pd, 2);
            ps += __shfl_xor(ps, 4); pd += __shfl_xor(pd, 4);
            ps += __shfl_xor(ps, 8); pd += __shfl_xor(pd, 8);
            if (r16 == 0 && r < N_NODES) {
                s_src[r * 8 + head] = ps;
                s_dst[r * 8 + head] = pd;
            }
        }
    }
}

// ---------------------------------------------------------------------------
// Edge score pass: lane-pair split (even lane: heads 0-3, odd: heads 4-7).
// Per edge-pair: ONE float4 gather per table per lane (32 distinct lines per
// 64-lane instruction instead of ~60) + half the per-lane online-softmax VALU.
// Writes t[8] per edge coalesced to tbuf (if provided) and per-block online
// (m,l) partials.
// ---------------------------------------------------------------------------
__global__ __launch_bounds__(256) void edge_score_kernel(
    const int* __restrict__ ei, const float* __restrict__ s_src,
    const float* __restrict__ s_dst, float* __restrict__ tbuf,
    float* __restrict__ partial)
{
    const int tid  = threadIdx.x;
    const int half = tid & 1;            // heads half*4 .. half*4+3

    float m[4], l[4];
    #pragma unroll
    for (int i = 0; i < 4; ++i) { m[i] = -1e30f; l[i] = 0.f; }

    for (int p = blockIdx.x * 128 + (tid >> 1); p < N_EDGES; p += gridDim.x * 128) {
        const int row = ei[p];
        const int col = ei[N_EDGES + p];
        const f32x4 s = *(const f32x4*)(s_src + row * 8 + half * 4);
        const f32x4 d = *(const f32x4*)(s_dst + col * 8 + half * 4);
        float t[4];
        #pragma unroll
        for (int i = 0; i < 4; ++i) {
            float v = s[i] + d[i];
            t[i] = v > 0.f ? v : 0.01f * v;       // leaky_relu 0.01
        }
        if (tbuf)
            *(float4*)(tbuf + (size_t)p * 8 + half * 4) =
                make_float4(t[0], t[1], t[2], t[3]);
        #pragma unroll
        for (int i = 0; i < 4; ++i) {             // branch-free online update
            const float mn = fmaxf(m[i], t[i]);
            l[i] = l[i] * __expf(m[i] - mn) + __expf(t[i] - mn);
            m[i] = mn;
        }
    }

    // block reduce; parity-preserving strides keep head mapping intact
    __shared__ float red[8][256];
    #pragma unroll
    for (int i = 0; i < 4; ++i) { red[i][tid] = m[i]; red[4 + i][tid] = l[i]; }
    __syncthreads();
    for (int s = 128; s >= 2; s >>= 1) {
        if (tid < s) {
            #pragma unroll
            for (int i = 0; i < 4; ++i) {
                const float mo = red[i][tid + s], lo = red[4 + i][tid + s];
                const float mm = red[i][tid],     ll = red[4 + i][tid];
                const float mn = fmaxf(mm, mo);
                red[4 + i][tid] = ll * __expf(mm - mn) + lo * __expf(mo - mn);
                red[i][tid]     = mn;
            }
        }
        __syncthreads();
    }
    if (tid < 2) {
        #pragma unroll
        for (int i = 0; i < 4; ++i) {
            partial[blockIdx.x * 16 + tid * 4 + i]     = red[i][tid];
            partial[blockIdx.x * 16 + 8 + tid * 4 + i] = red[4 + i][tid];
        }
    }
}

// ---------------------------------------------------------------------------
// Merge partials. coef[h]=M_h, coef[8+h]=g_h/L_h, coef[16+h]=skip cutoff.
// 256 threads (32 chunks/head) to cut the serial L2-latency chain.
// ---------------------------------------------------------------------------
__global__ __launch_bounds__(256) void finalize_kernel(
    const float* __restrict__ partial, const float* __restrict__ gate,
    float* __restrict__ coef, int nblk)
{
    const int t = threadIdx.x;
    const int h = t & 7;
    const int j = t >> 3;                 // 0..31
    float m = -1e30f, l = 0.f;
    for (int bk = j; bk < nblk; bk += 32) {
        const float mb = partial[bk * 16 + h];
        const float lb = partial[bk * 16 + 8 + h];
        const float mn = fmaxf(m, mb);
        l = l * __expf(m - mn) + lb * __expf(mb - mn);
        m = mn;
    }
    __shared__ float rm[256], rl[256];
    rm[t] = m; rl[t] = l;
    __syncthreads();
    for (int s = 128; s >= 8; s >>= 1) {
        if (t < s) {
            const float mo = rm[t + s], lo = rl[t + s];
            const float mn = fmaxf(rm[t], mo);
            rl[t] = rl[t] * __expf(rm[t] - mn) + lo * __expf(mo - mn);
            rm[t] = mn;
        }
        __syncthreads();
    }
    if (t < 8) {
        float gm = gate[0];
        for (int i = 1; i < 8; ++i) gm = fmaxf(gm, gate[i]);
        float gs = 0.f;
        for (int i = 0; i < 8; ++i) gs += __expf(gate[i] - gm);
        const float g = __expf(gate[t] - gm) / gs;
        const float C = g / rl[t];
        coef[t]      = rm[t];
        coef[8 + t]  = C;
        coef[16 + t] = rm[t] + LN_W_EPS - __logf(C);   // t >= cut  <=>  w >= eps
    }
}

// ---------------------------------------------------------------------------
// Thresholded scatter, t-buffer path: coalesced 32B read per edge, ei loaded
// only for the rare passing edges; wave-cooperative Wh gather (permuted idx).
// ---------------------------------------------------------------------------
__global__ __launch_bounds__(256) void scatter_t_kernel(
    const int* __restrict__ ei, const float* __restrict__ tbuf,
    const float* __restrict__ Wh, const float* __restrict__ coef,
    float* __restrict__ out)
{
    __shared__ float cM[8], cC[8], cCut[8];
    if (threadIdx.x < 8)       cM[threadIdx.x]        = coef[threadIdx.x];
    else if (threadIdx.x < 16) cC[threadIdx.x - 8]    = coef[threadIdx.x];
    else if (threadIdx.x < 24) cCut[threadIdx.x - 16] = coef[threadIdx.x];
    __syncthreads();

    const int lane = threadIdx.x & 63;
    const int e    = blockIdx.x * 256 + threadIdx.x;

    int row = 0, col = 0;
    bool pass = false;
    float t[8], w[8];
    if (e < N_EDGES) {
        const float4 t0 = *(const float4*)(tbuf + (size_t)e * 8);
        const float4 t1 = *(const float4*)(tbuf + (size_t)e * 8 + 4);
        t[0] = t0.x; t[1] = t0.y; t[2] = t0.z; t[3] = t0.w;
        t[4] = t1.x; t[5] = t1.y; t[6] = t1.z; t[7] = t1.w;
        #pragma unroll
        for (int h = 0; h < 8; ++h) pass |= (t[h] >= cCut[h]);
    }
    if (pass) {
        row = ei[e];
        col = ei[N_EDGES + e];
        #pragma unroll
        for (int h = 0; h < 8; ++h)
            w[h] = __expf(t[h] - cM[h]) * cC[h];
    }

    unsigned long long mask = __ballot(pass);
    while (mask) {
        const int src = (int)__builtin_ctzll(mask);
        mask &= mask - 1;
        const int rb = __shfl(row, src);
        const int cb = __shfl(col, src);
        // permuted Wh row: element (h, o) at h*64 + (o&15)*4 + (o>>4)
        const float* wc = Wh + (size_t)cb * NCOL + (lane & 15) * 4 + (lane >> 4);
        float acc = 0.f;
        #pragma unroll
        for (int h = 0; h < 8; ++h)
            acc += __shfl(w[h], src) * wc[h * 64];
        atomicAdd(out + (size_t)rb * OUT_DIM + lane, acc);
    }
}

// ---------------------------------------------------------------------------
// Fallback scatter (no tbuf space): recompute scores from gathers (verified
// round-1 path, Wh index updated for the permuted layout).
// ---------------------------------------------------------------------------
__global__ __launch_bounds__(256) void scatter_kernel(
    const int* __restrict__ ei, const float* __restrict__ s_src,
    const float* __restrict__ s_dst, const float* __restrict__ Wh,
    const float* __restrict__ coef, float* __restrict__ out)
{
    __shared__ float cM[8], cC[8], cCut[8];
    if (threadIdx.x < 8)       cM[threadIdx.x]        = coef[threadIdx.x];
    else if (threadIdx.x < 16) cC[threadIdx.x - 8]    = coef[threadIdx.x];
    else if (threadIdx.x < 24) cCut[threadIdx.x - 16] = coef[threadIdx.x];
    __syncthreads();

    const int lane = threadIdx.x & 63;
    const int e    = blockIdx.x * 256 + threadIdx.x;

    int row = 0, col = 0;
    bool pass = false;
    float w[8];
    if (e < N_EDGES) {
        row = ei[e];
        col = ei[N_EDGES + e];
        const float4 s0 = *(const float4*)(s_src + row * 8);
        const float4 s1 = *(const float4*)(s_src + row * 8 + 4);
        const float4 d0 = *(const float4*)(s_dst + col * 8);
        const float4 d1 = *(const float4*)(s_dst + col * 8 + 4);
        float t[8] = { s0.x + d0.x, s0.y + d0.y, s0.z + d0.z, s0.w + d0.w,
                       s1.x + d1.x, s1.y + d1.y, s1.z + d1.z, s1.w + d1.w };
        #pragma unroll
        for (int h = 0; h < 8; ++h) {
            t[h] = t[h] > 0.f ? t[h] : 0.01f * t[h];
            pass |= (t[h] >= cCut[h]);
        }
        if (pass) {
            #pragma unroll
            for (int h = 0; h < 8; ++h)
                w[h] = __expf(t[h] - cM[h]) * cC[h];
        }
    }

    unsigned long long mask = __ballot(pass);
    while (mask) {
        const int src = (int)__builtin_ctzll(mask);
        mask &= mask - 1;
        const int rb = __shfl(row, src);
        const int cb = __shfl(col, src);
        const float* wc = Wh + (size_t)cb * NCOL + (lane & 15) * 4 + (lane >> 4);
        float acc = 0.f;
        #pragma unroll
        for (int h = 0; h < 8; ++h)
            acc += __shfl(w[h], src) * wc[h * 64];
        atomicAdd(out + (size_t)rb * OUT_DIM + lane, acc);
    }
}

// ---------------------------------------------------------------------------
extern "C" void kernel_launch(void* const* d_in, const int* in_sizes, int n_in,
                              void* d_out, int out_size, void* d_ws, size_t ws_size,
                              hipStream_t stream)
{
    const float* x    = (const float*)d_in[0];
    const int*   ei   = (const int*)  d_in[1];
    const float* W    = (const float*)d_in[2];
    const float* b    = (const float*)d_in[3];
    const float* a    = (const float*)d_in[4];
    const float* gate = (const float*)d_in[5];
    float* out = (float*)d_out;

    // workspace layout (floats): Wh | s_src | s_dst | partial | coef | wp | tbuf
    float* ws      = (float*)d_ws;
    float* Wh      = ws;
    float* s_src   = Wh    + (size_t)N_NODES * NCOL;
    float* s_dst   = s_src + (size_t)N_NODES * HEADS;
    float* partial = s_dst + (size_t)N_NODES * HEADS;
    float* coef    = partial + (size_t)NBLK_RED * 16;
    short* wp      = (short*)(coef + 32);              // 512 KB, 16B-aligned
    float* tbuf    = (float*)(wp + 262144);            // 25.6 MB (optional)

    const size_t base_bytes = (size_t)((char*)tbuf - (char*)ws);
    const size_t need_tbuf  = base_bytes + (size_t)N_EDGES * 8 * sizeof(float);
    const bool   use_tbuf   = ws_size >= need_tbuf;

    hipMemsetAsync(d_out, 0, (size_t)N_NODES * OUT_DIM * sizeof(float), stream);

    packw_kernel<<<32, 256, 0, stream>>>(W, wp);

    gemm_kernel<<<(N_NODES + 63) / 64, 512, 0, stream>>>(x, wp, b, a, Wh, s_src, s_dst);

    edge_score_kernel<<<NBLK_RED, 256, 0, stream>>>(
        ei, s_src, s_dst, use_tbuf ? tbuf : nullptr, partial);

    finalize_kernel<<<1, 256, 0, stream>>>(partial, gate, coef, NBLK_RED);

    if (use_tbuf)
        scatter_t_kernel<<<(N_EDGES + 255) / 256, 256, 0, stream>>>(
            ei, tbuf, Wh, coef, out);
    else
        scatter_kernel<<<(N_EDGES + 255) / 256, 256, 0, stream>>>(
            ei, s_src, s_dst, Wh, coef, out);
}